// Round 11
// baseline (311.858 us; speedup 1.0000x reference)
//
#include <hip/hip_runtime.h>
#include <hip/hip_bf16.h>

// QuantizedLinearINT4: out = x @ dequant(W).T + bias
// M=8192, N=OUT=4096, K=IN=4096.
// Round-11: bf16-B numerics (round-4: VALU-light) x 2-async-blocks/CU
// (round-10: fills barrier idle). Tile 256x128, BK=32, triple-buffered LDS
// (72 KiB/block -> 2 blocks/CU), 256 thr (4 waves 2Mx2N), counted vmcnt(6)
// with 2-phase staging lead, st_16x32 swizzle, XCD swizzle, setprio.
// Prep: pass-1 dequant W int4->bf16, pass-2 cvt x f32->bf16.

typedef __bf16 bf16;
typedef __attribute__((ext_vector_type(8))) __bf16 bf16x8;
typedef __attribute__((ext_vector_type(4))) float f32x4;
typedef __attribute__((ext_vector_type(4))) unsigned int u32x4;

#define OUT_DIM 4096
#define IN_DIM  4096
#define M_DIM   8192

// ---------- Pass 1: dequant int4 -> bf16 W[OUT][IN] (round-1 proven) ----------
__global__ __launch_bounds__(256) void dequant_w_kernel(
    const int* __restrict__ wp, const float* __restrict__ scale,
    const float* __restrict__ zp, bf16* __restrict__ W)
{
  const int t = blockIdx.x * 256 + threadIdx.x;
  const long j = (long)t * 8;
  const int o = (int)(j >> 12);
  const float s = scale[o];
  const float zs = zp[o] * s;
  const int4 p = *(const int4*)(wp + (long)t * 4);
  const int v[4] = {p.x, p.y, p.z, p.w};
  union { bf16 h[8]; u32x4 u; } r;
#pragma unroll
  for (int q = 0; q < 4; ++q) {
    r.h[2*q]   = (bf16)((float)(v[q] & 15) * s - zs);
    r.h[2*q+1] = (bf16)((float)((v[q] >> 4) & 15) * s - zs);
  }
  *(u32x4*)(W + j) = r.u;
}

// ---------- Pass 2: cast x f32 -> bf16 ----------
__global__ __launch_bounds__(256) void cvt_x_kernel(
    const float* __restrict__ x, bf16* __restrict__ xb)
{
  const long t = (long)blockIdx.x * 256 + threadIdx.x;
  const long i = t * 8;
  const f32x4 a = *(const f32x4*)(x + i);
  const f32x4 b = *(const f32x4*)(x + i + 4);
  union { bf16 h[8]; u32x4 u; } r;
#pragma unroll
  for (int q = 0; q < 4; ++q) { r.h[q] = (bf16)a[q]; r.h[4+q] = (bf16)b[q]; }
  *(u32x4*)(xb + i) = r.u;
}

// ---------- Pass 3: 256x128 tile, BK=32, 4 waves, 2 blocks/CU ----------
// C[M][N] = A[M][K] * B[N][K]^T + bias.  Per wave 128x64 out (acc[8][4]).
// LDS: smA[3][256][32] + smB[3][128][32] bf16 = 72 KiB, st_16x32 swizzle,
// linear gload_lds dest + pre-swizzled global src + swizzled ds_read.
// Phase T (one 32-K tile): vmcnt(6) -> barrier -> 12 ds_read_b128 ->
// stage tile T+2 (6 gload_lds) -> 32 MFMA (compiler-counted lgkm).
__global__ __launch_bounds__(256, 2) void gemm_bt_bias_kernel(
    const bf16* __restrict__ A, const bf16* __restrict__ B,
    const float* __restrict__ bias, float* __restrict__ C)
{
  const int N = OUT_DIM, K = IN_DIM;
  const int NT = IN_DIM / 32;            // 128 K-tiles (one phase each)

  __shared__ bf16 smA[3][256][32];       // 48 KiB
  __shared__ bf16 smB[3][128][32];       // 24 KiB

  // T1: XCD-aware bijective swizzle (1024 blocks, % 8 == 0)
  const int bid = blockIdx.x;
  const int swz = (bid & 7) * 128 + (bid >> 3);
  const int bm = swz >> 5;               // 32 M-tiles (256 rows)
  const int bn = swz & 31;               // 32 N-tiles (128 cols)

  const int tid  = threadIdx.x;
  const int lane = tid & 63;
  const int wave = tid >> 6;             // 0..3
  const int wr = wave >> 1;              // 0..1 -> 128-row strip
  const int wc = wave & 1;               // 0..1 -> 64-col strip

  const long row0 = (long)bm * 256;
  const long col0 = (long)bn * 128;

  // --- staging sources (pre-swizzled: linear LDS dest, swizzled global src) ---
  const int LA = tid * 16;
  const bf16 *aP0, *aP1, *aP2, *aP3, *bP0, *bP1;
#define MKS(c, P, BASE, C0) { const int L = (c)*4096 + tid*16;                  \
    const int Lw = L ^ (((L >> 9) & 1) << 5);                                   \
    P = (BASE) + ((C0) + (Lw >> 6)) * (long)K + ((Lw & 63) >> 1); }
  MKS(0, aP0, A, row0) MKS(1, aP1, A, row0) MKS(2, aP2, A, row0) MKS(3, aP3, A, row0)
  MKS(0, bP0, B, col0) MKS(1, bP1, B, col0)
#undef MKS

#define GL(P, D) __builtin_amdgcn_global_load_lds(                              \
      (const __attribute__((address_space(1))) void*)(P),                       \
      (__attribute__((address_space(3))) void*)(D), 16, 0, 0)

#define STAGE_TILE(BUF, KOFF) do {                                              \
    char* Ah = (char*)&smA[BUF][0][0];                                          \
    char* Bh = (char*)&smB[BUF][0][0];                                          \
    GL(aP0 + (KOFF), Ah + LA);                                                  \
    GL(aP1 + (KOFF), Ah + 4096 + LA);                                           \
    GL(aP2 + (KOFF), Ah + 8192 + LA);                                           \
    GL(aP3 + (KOFF), Ah + 12288 + LA);                                          \
    GL(bP0 + (KOFF), Bh + LA);                                                  \
    GL(bP1 + (KOFF), Bh + 4096 + LA);                                           \
  } while (0)

  // --- ds_read per-lane constants (swizzle folds to ^((lane&8)<<2)) ---
  const int lane15 = lane & 15;
  const int rb  = (lane15 * 64 + ((lane >> 4) << 4)) ^ ((lane & 8) << 2);
  const int wrB = wr * 8192;             // A: wave's 128-row strip byte offset
  const int wcB = wc * 4096;             // B: wave's 64-row strip byte offset

  f32x4 acc[8][4] = {};

  // Prologue: stage tiles 0,1 -> bufs 0,1 (12 loads in flight)
  STAGE_TILE(0, 0);
  STAGE_TILE(1, 32);

  int bufT = 0, buf2 = 2;
  for (int T = 0; T < NT; ++T) {
    if (T == NT - 1) asm volatile("s_waitcnt vmcnt(0)" ::: "memory");
    else             asm volatile("s_waitcnt vmcnt(6)" ::: "memory");
    __builtin_amdgcn_s_barrier();
    asm volatile("" ::: "memory");       // keep ds_reads below the barrier

    const char* Ab = (const char*)&smA[bufT][0][0];
    const char* Bb = (const char*)&smB[bufT][0][0];
    bf16x8 fb[4], fa[8];
#pragma unroll
    for (int f = 0; f < 4; ++f) fb[f] = *(const bf16x8*)(Bb + wcB + f * 1024 + rb);
#pragma unroll
    for (int f = 0; f < 8; ++f) fa[f] = *(const bf16x8*)(Ab + wrB + f * 1024 + rb);

    if (T + 2 < NT) STAGE_TILE(buf2, (T + 2) * 32);

    __builtin_amdgcn_s_setprio(1);
#pragma unroll
    for (int i = 0; i < 8; ++i)
#pragma unroll
      for (int j = 0; j < 4; ++j)
        acc[i][j] = __builtin_amdgcn_mfma_f32_16x16x32_bf16(fa[i], fb[j], acc[i][j], 0, 0, 0);
    __builtin_amdgcn_s_setprio(0);

    bufT = (bufT == 2) ? 0 : bufT + 1;
    buf2 = (buf2 == 2) ? 0 : buf2 + 1;
  }

  // Epilogue: C/D layout col=lane&15, row=(lane>>4)*4+reg; fused bias.
  const long cr0 = row0 + wr * 128 + ((lane >> 4) << 2);
  const long cc0 = col0 + wc * 64 + lane15;
#pragma unroll
  for (int j = 0; j < 4; ++j) {
    const long gc = cc0 + j * 16;
    const float bv = bias[gc];
#pragma unroll
    for (int mf = 0; mf < 8; ++mf) {
      float* cp = C + (cr0 + mf * 16) * (long)N + gc;
#pragma unroll
      for (int r = 0; r < 4; ++r)
        cp[(long)r * N] = acc[mf][j][r] + bv;
    }
  }
#undef STAGE_TILE
#undef GL
}

extern "C" void kernel_launch(void* const* d_in, const int* in_sizes, int n_in,
                              void* d_out, int out_size, void* d_ws, size_t ws_size,
                              hipStream_t stream)
{
  const float* x     = (const float*)d_in[0];
  const int*   wp    = (const int*)d_in[1];
  const float* scale = (const float*)d_in[2];
  const float* zp    = (const float*)d_in[3];
  const float* bias  = (const float*)d_in[4];
  float* out = (float*)d_out;

  bf16* Wb = (bf16*)d_ws;                                         // 33,554,432 B
  bf16* Xb = (bf16*)((char*)d_ws + (size_t)OUT_DIM * IN_DIM * 2); // 67,108,864 B

  dequant_w_kernel<<<(OUT_DIM * (long)IN_DIM / 8) / 256, 256, 0, stream>>>(wp, scale, zp, Wb);
  cvt_x_kernel<<<(M_DIM * (long)IN_DIM / 8) / 256, 256, 0, stream>>>(x, Xb);
  // grid = (8192/256)*(4096/128) = 32*32 = 1024 blocks, 256 threads
  gemm_bt_bias_kernel<<<1024, 256, 0, stream>>>(Xb, Wb, bias, out);
}